// Round 8
// baseline (80.066 us; speedup 1.0000x reference)
//
#include <hip/hip_runtime.h>
#include <hip/hip_bf16.h>

#define NTOK 1024
#define EMB  1024
#define NH   16
#define HD   64
#define NS   128

typedef unsigned short u16;
typedef unsigned int uint;
typedef __attribute__((ext_vector_type(8))) unsigned short ushort8v;
typedef __attribute__((ext_vector_type(8))) _Float16 half8v;
typedef __attribute__((ext_vector_type(4))) float f32x4;

__device__ __forceinline__ u16 f2h_bits(float f) {
  union { _Float16 h; u16 u; } x; x.h = (_Float16)f; return x.u;
}

// ---------------------------------------------------------------------------
// fp32 -> f16 converter. grid(1024, Z): z selects src matrix; dst contiguous.
// Each thread converts one float4 -> ushort4 (exactly 1M elems per z-slice).
// ---------------------------------------------------------------------------
__global__ __launch_bounds__(256) void cvt_w(const float* __restrict__ S0,
                                             const float* __restrict__ S1,
                                             const float* __restrict__ S2,
                                             u16* __restrict__ D) {
  const int z = blockIdx.y;
  const float* S = (z == 0) ? S0 : ((z == 1) ? S1 : S2);
  const int idx = blockIdx.x * 256 + threadIdx.x;          // 0..262143
  const float4 f = ((const float4*)S)[idx];
  ushort4 p;
  p.x = f2h_bits(f.x); p.y = f2h_bits(f.y);
  p.z = f2h_bits(f.z); p.w = f2h_bits(f.w);
  ((ushort4*)(D + (size_t)z * 1024 * 1024))[idx] = p;
}

// ---------------------------------------------------------------------------
// GEMM: C[M,N] = A[M,K] * B[N,K]^T + bias[N], M=N=K=1024.
// B is PRE-CONVERTED f16 (pure ushort8 copy staging). A fp32 or f16.
// 64x64 tile, BK=64, 256 threads (4 waves, 2x2 of 32x32), 8 MFMA/wave/step.
// LDS row stride 72 u16 = 144 B (2-way bank aliasing on frag reads = free).
// OUT_F16 && z==2 stores C transposed (Vt[d][token]) for the attention PV.
// ---------------------------------------------------------------------------
template<bool A_F16, bool OUT_F16>
__global__ __launch_bounds__(256) void gemm_f16b(
    const void* __restrict__ A0, const void* __restrict__ A1, const void* __restrict__ A2,
    const u16* __restrict__ B0, const u16* __restrict__ B1, const u16* __restrict__ B2,
    const float* __restrict__ b0, const float* __restrict__ b1, const float* __restrict__ b2,
    void* __restrict__ Cp) {
  __shared__ u16 As[64 * 72];
  __shared__ u16 Bs[64 * 72];

  const int t = threadIdx.x;
  const int lane = t & 63;
  const int w = t >> 6;
  const int wr = w >> 1, wc = w & 1;
  const int m0 = blockIdx.y * 64;
  const int n0 = blockIdx.x * 64;
  const int z = blockIdx.z;

  const void* Asel = (z == 0) ? A0 : ((z == 1) ? A1 : A2);
  const u16*  Bsel = (z == 0) ? B0 : ((z == 1) ? B1 : B2);
  const float* bsel = (z == 0) ? b0 : ((z == 1) ? b1 : b2);

  const int srow = t >> 2;         // 0..63
  const int scol = (t & 3) * 16;   // 0,16,32,48

  f32x4 acc[2][2];
#pragma unroll
  for (int m = 0; m < 2; m++)
#pragma unroll
    for (int n = 0; n < 2; n++) acc[m][n] = (f32x4){0.f, 0.f, 0.f, 0.f};

  const int fr = lane & 15;
  const int fq = lane >> 4;

  for (int k0 = 0; k0 < 1024; k0 += 64) {
    // ---- stage A (64 rows x 64 k) ----
    if constexpr (A_F16) {
      const u16* ap = (const u16*)Asel + (size_t)(m0 + srow) * 1024 + k0 + scol;
      *(ushort8v*)&As[srow * 72 + scol]     = ((const ushort8v*)ap)[0];
      *(ushort8v*)&As[srow * 72 + scol + 8] = ((const ushort8v*)ap)[1];
    } else {
      const float* ap = (const float*)Asel + (size_t)(m0 + srow) * 1024 + k0 + scol;
      const float4 f0 = ((const float4*)ap)[0];
      const float4 f1 = ((const float4*)ap)[1];
      const float4 f2 = ((const float4*)ap)[2];
      const float4 f3 = ((const float4*)ap)[3];
      ushort8v p0, p1;
      p0[0] = f2h_bits(f0.x); p0[1] = f2h_bits(f0.y); p0[2] = f2h_bits(f0.z); p0[3] = f2h_bits(f0.w);
      p0[4] = f2h_bits(f1.x); p0[5] = f2h_bits(f1.y); p0[6] = f2h_bits(f1.z); p0[7] = f2h_bits(f1.w);
      p1[0] = f2h_bits(f2.x); p1[1] = f2h_bits(f2.y); p1[2] = f2h_bits(f2.z); p1[3] = f2h_bits(f2.w);
      p1[4] = f2h_bits(f3.x); p1[5] = f2h_bits(f3.y); p1[6] = f2h_bits(f3.z); p1[7] = f2h_bits(f3.w);
      *(ushort8v*)&As[srow * 72 + scol]     = p0;
      *(ushort8v*)&As[srow * 72 + scol + 8] = p1;
    }
    // ---- stage B (always f16: pure copy) ----
    {
      const u16* bp = Bsel + (size_t)(n0 + srow) * 1024 + k0 + scol;
      *(ushort8v*)&Bs[srow * 72 + scol]     = ((const ushort8v*)bp)[0];
      *(ushort8v*)&Bs[srow * 72 + scol + 8] = ((const ushort8v*)bp)[1];
    }
    __syncthreads();

#pragma unroll
    for (int kk = 0; kk < 2; kk++) {
      const int kc = kk * 32 + fq * 8;
      half8v a[2], b[2];
#pragma unroll
      for (int m = 0; m < 2; m++)
        a[m] = *(const half8v*)&As[(wr * 32 + m * 16 + fr) * 72 + kc];
#pragma unroll
      for (int n = 0; n < 2; n++)
        b[n] = *(const half8v*)&Bs[(wc * 32 + n * 16 + fr) * 72 + kc];
#pragma unroll
      for (int m = 0; m < 2; m++)
#pragma unroll
        for (int n = 0; n < 2; n++)
          acc[m][n] = __builtin_amdgcn_mfma_f32_16x16x32_f16(a[m], b[n], acc[m][n], 0, 0, 0);
    }
    __syncthreads();
  }

  u16*   Cb = (u16*)Cp   + (size_t)z * 1024 * 1024;
  float* Cf = (float*)Cp + (size_t)z * 1024 * 1024;

  if (OUT_F16 && z == 2) {
    // transposed store: Vt[col][row]
#pragma unroll
    for (int n = 0; n < 2; n++) {
      const int col = n0 + wc * 32 + n * 16 + fr;
      const float bn = bsel[col];
#pragma unroll
      for (int m = 0; m < 2; m++) {
        const int rbase = m0 + wr * 32 + m * 16 + fq * 4;
        ushort4 pk;
        pk.x = f2h_bits(acc[m][n][0] + bn);
        pk.y = f2h_bits(acc[m][n][1] + bn);
        pk.z = f2h_bits(acc[m][n][2] + bn);
        pk.w = f2h_bits(acc[m][n][3] + bn);
        *(ushort4*)&Cb[(size_t)col * 1024 + rbase] = pk;
      }
    }
    return;
  }

#pragma unroll
  for (int n = 0; n < 2; n++) {
    const int col = n0 + wc * 32 + n * 16 + fr;
    const float bn = bsel[col];
#pragma unroll
    for (int m = 0; m < 2; m++) {
      const int rbase = m0 + wr * 32 + m * 16 + fq * 4;
#pragma unroll
      for (int r = 0; r < 4; r++) {
        const float val = acc[m][n][r] + bn;
        if constexpr (OUT_F16)
          Cb[(size_t)(rbase + r) * 1024 + col] = f2h_bits(val);
        else
          Cf[(size_t)(rbase + r) * 1024 + col] = val;
      }
    }
  }
}

// ---------------------------------------------------------------------------
// Sampled-set bitmask: mask[i] has bit j set iff j ∈ samples[i,:].
// ---------------------------------------------------------------------------
__global__ __launch_bounds__(128) void mask_build(const int* __restrict__ samples,
                                                  uint* __restrict__ maskg) {
  const int i = blockIdx.x;
  const int t = threadIdx.x;
  __shared__ uint m[32];
  if (t < 32) m[t] = 0u;
  __syncthreads();
  const int c = samples[(size_t)i * NS + t];
  atomicOr(&m[c >> 5], 1u << (c & 31));
  __syncthreads();
  if (t < 32) maskg[(size_t)i * 32 + t] = m[t];
}

// ---------------------------------------------------------------------------
// Dense masked attention, f16 MFMA (unchanged from R7).
// ---------------------------------------------------------------------------
__global__ __launch_bounds__(128) void attn6(const u16* __restrict__ Qh,
                                             const u16* __restrict__ Kh,
                                             const u16* __restrict__ Vtg,
                                             const uint* __restrict__ maskg,
                                             u16* __restrict__ O) {
  const int h  = blockIdx.x;
  const int qt = blockIdx.y;
  const int t  = threadIdx.x;
  const int wid = t >> 6;
  const int lane = t & 63;
  const int fr = lane & 15, fq = lane >> 4;

  __shared__ u16 Ks[128][72];
  __shared__ u16 Vs[64][136];
  __shared__ u16 Ps[2][16][136];
  __shared__ uint Ms[32][32];

#pragma unroll
  for (int wi = 0; wi < 8; wi++)
    ((uint*)Ms)[wi * 128 + t] = maskg[(size_t)qt * 32 * 32 + wi * 128 + t];

  half8v qa0, qa1;
  {
    const u16* qp = Qh + (size_t)(qt * 32 + wid * 16 + fr) * EMB + h * HD + fq * 8;
    qa0 = *(const half8v*)qp;
    qa1 = *(const half8v*)(qp + 32);
  }

  f32x4 oacc[4];
#pragma unroll
  for (int ds = 0; ds < 4; ds++) oacc[ds] = (f32x4){0.f, 0.f, 0.f, 0.f};
  float lsum[4] = {0.f, 0.f, 0.f, 0.f};

  for (int kt = 0; kt < 8; kt++) {
    __syncthreads();
    {
      const u16* kp = Kh + (size_t)(kt * 128 + (t >> 3)) * EMB + h * HD + (t & 7) * 8;
#pragma unroll
      for (int ii = 0; ii < 8; ii++)
        *(ushort8v*)&Ks[(t >> 3) + ii * 16][(t & 7) * 8] =
            *(const ushort8v*)(kp + (size_t)ii * 16 * EMB);
      const u16* vp = Vtg + (size_t)(h * HD + (t >> 4)) * NTOK + kt * 128 + (t & 15) * 8;
#pragma unroll
      for (int ii = 0; ii < 8; ii++)
        *(ushort8v*)&Vs[(t >> 4) + ii * 8][(t & 15) * 8] =
            *(const ushort8v*)(vp + (size_t)ii * 8 * NTOK);
    }
    __syncthreads();

#pragma unroll
    for (int jb = 0; jb < 8; jb++) {
      f32x4 s = (f32x4){0.f, 0.f, 0.f, 0.f};
      const half8v b0 = *(const half8v*)&Ks[jb * 16 + fr][fq * 8];
      const half8v b1 = *(const half8v*)&Ks[jb * 16 + fr][32 + fq * 8];
      s = __builtin_amdgcn_mfma_f32_16x16x32_f16(qa0, b0, s, 0, 0, 0);
      s = __builtin_amdgcn_mfma_f32_16x16x32_f16(qa1, b1, s, 0, 0, 0);
      const int mword = (kt * 128 + jb * 16) >> 5;
      const int mbit  = (jb & 1) * 16 + fr;
#pragma unroll
      for (int r = 0; r < 4; r++) {
        const uint mw = Ms[wid * 16 + fq * 4 + r][mword];
        const float p = ((mw >> mbit) & 1u) ? __expf(s[r] * 0.03125f) : 0.f;
        lsum[r] += p;
        Ps[wid][fq * 4 + r][jb * 16 + fr] = f2h_bits(p);
      }
    }
    asm volatile("s_waitcnt lgkmcnt(0)" ::: "memory");

#pragma unroll
    for (int jc = 0; jc < 4; jc++) {
      const half8v pa = *(const half8v*)&Ps[wid][fr][jc * 32 + fq * 8];
#pragma unroll
      for (int ds = 0; ds < 4; ds++) {
        const half8v vb = *(const half8v*)&Vs[ds * 16 + fr][jc * 32 + fq * 8];
        oacc[ds] = __builtin_amdgcn_mfma_f32_16x16x32_f16(pa, vb, oacc[ds], 0, 0, 0);
      }
    }
  }

#pragma unroll
  for (int r = 0; r < 4; r++) {
    float v = lsum[r];
#pragma unroll
    for (int off = 1; off < 16; off <<= 1) v += __shfl_xor(v, off, 16);
    lsum[r] = v;
  }

#pragma unroll
  for (int ds = 0; ds < 4; ds++) {
#pragma unroll
    for (int r = 0; r < 4; r++) {
      O[(size_t)(qt * 32 + wid * 16 + fq * 4 + r) * EMB + h * HD + ds * 16 + fr] =
          f2h_bits(oacc[ds][r] / lsum[r]);
    }
  }
}

extern "C" void kernel_launch(void* const* d_in, const int* in_sizes, int n_in,
                              void* d_out, int out_size, void* d_ws, size_t ws_size,
                              hipStream_t stream) {
  const float* query = (const float*)d_in[0];
  const float* key   = (const float*)d_in[1];
  const float* value = (const float*)d_in[2];
  const float* Wq    = (const float*)d_in[3];
  const float* bq    = (const float*)d_in[4];
  const float* Wk    = (const float*)d_in[5];
  const float* bk    = (const float*)d_in[6];
  const float* Wv    = (const float*)d_in[7];
  const float* bv    = (const float*)d_in[8];
  const float* Wo    = (const float*)d_in[9];
  const float* bo    = (const float*)d_in[10];
  const int* samples = (const int*)d_in[11];
  float* out = (float*)d_out;

  // ws (14.125 MB total, <= proven-safe 14.25):
  //   Wh: 6 MB f16 weights (Wq,Wk,Wv; after QKV GEMM, Wo overwrites Wh[0:1M))
  //   Qh,Kh,Vt,O: 8 MB; mask: 128 KB
  u16* Wh = (u16*)d_ws;
  u16* Qh = Wh + (size_t)3 * 1024 * 1024;
  u16* Kh = Qh + (size_t)NTOK * EMB;
  u16* Vt = Kh + (size_t)NTOK * EMB;
  u16* O  = Vt + (size_t)NTOK * EMB;
  uint* maskg = (uint*)(O + (size_t)NTOK * EMB);

  mask_build<<<NTOK, NS, 0, stream>>>(samples, maskg);

  cvt_w<<<dim3(1024, 3), 256, 0, stream>>>(Wq, Wk, Wv, Wh);

  gemm_f16b<false, true><<<dim3(16, 16, 3), 256, 0, stream>>>(
      query, key, value,
      Wh, Wh + (size_t)1024 * 1024, Wh + (size_t)2 * 1024 * 1024,
      bq, bk, bv, Qh);

  // Wq-f16 region is dead now; convert Wo into it (stream-ordered).
  cvt_w<<<dim3(1024, 1), 256, 0, stream>>>(Wo, Wo, Wo, Wh);

  attn6<<<dim3(NH, 32), 128, 0, stream>>>(Qh, Kh, Vt, maskg, O);

  gemm_f16b<true, false><<<dim3(16, 16, 1), 256, 0, stream>>>(
      O, O, O, Wh, Wh, Wh, bo, bo, bo, out);
}

// Round 9
// 69.524 us; speedup vs baseline: 1.1516x; 1.1516x over previous
//
#include <hip/hip_runtime.h>
#include <hip/hip_bf16.h>

#define NTOK 1024
#define EMB  1024
#define NH   16
#define HD   64
#define NS   128

typedef unsigned short u16;
typedef unsigned int uint;
typedef __attribute__((ext_vector_type(8))) unsigned short ushort8v;
typedef __attribute__((ext_vector_type(8))) _Float16 half8v;
typedef __attribute__((ext_vector_type(4))) float f32x4;

__device__ __forceinline__ u16 f2h_bits(float f) {
  union { _Float16 h; u16 u; } x; x.h = (_Float16)f; return x.u;
}

__device__ __forceinline__ void gload16(const u16* g, u16* l) {
  __builtin_amdgcn_global_load_lds(
      (const __attribute__((address_space(1))) uint*)g,
      (__attribute__((address_space(3))) uint*)l, 16, 0, 0);
}

// ---------------------------------------------------------------------------
// fp32 -> f16 converter, 7 slices: z 0-2 = query/key/value, 3-6 = Wq/Wk/Wv/Wo.
// Dst = D + z * 1M elems. One float4 per thread.
// ---------------------------------------------------------------------------
__global__ __launch_bounds__(256) void cvt7(const float* __restrict__ S0,
                                            const float* __restrict__ S1,
                                            const float* __restrict__ S2,
                                            const float* __restrict__ S3,
                                            const float* __restrict__ S4,
                                            const float* __restrict__ S5,
                                            const float* __restrict__ S6,
                                            u16* __restrict__ D) {
  const int z = blockIdx.y;
  const float* S;
  switch (z) {
    case 0: S = S0; break;
    case 1: S = S1; break;
    case 2: S = S2; break;
    case 3: S = S3; break;
    case 4: S = S4; break;
    case 5: S = S5; break;
    default: S = S6; break;
  }
  const int idx = blockIdx.x * 256 + threadIdx.x;     // 0..262143
  const float4 f = ((const float4*)S)[idx];
  ushort4 p;
  p.x = f2h_bits(f.x); p.y = f2h_bits(f.y);
  p.z = f2h_bits(f.z); p.w = f2h_bits(f.w);
  ((ushort4*)(D + ((size_t)z << 20)))[idx] = p;
}

// ---------------------------------------------------------------------------
// 2-phase double-buffered f16 GEMM: C[M,N] = A[M,K]*B[N,K]^T + bias[N].
// 64x64 tile, BK=32, 256 threads (4 waves, 2x2 of 32x32), one barrier/K-step.
// Staging via global_load_lds (16B/lane, linear LDS dest); bank conflicts
// killed by source-side XOR swizzle chunk^=((row>>1)&3) with the matching
// XOR on the ds_read side (both-sides involution, rule m104/m231).
// A,B slices selected by blockIdx.z (+z*1M elems each); C likewise.
// OUT_F16 && z==2 stores C transposed (Vt[d][token]) for the attention.
// ---------------------------------------------------------------------------
template<bool OUT_F16>
__global__ __launch_bounds__(256) void gemm2ph(const u16* __restrict__ Ab,
                                               const u16* __restrict__ Bb,
                                               const float* __restrict__ b0,
                                               const float* __restrict__ b1,
                                               const float* __restrict__ b2,
                                               void* __restrict__ Cp) {
  __shared__ u16 buf[2][2][64 * 32];   // [dbuf][A/B][row*32+col]  16 KB

  const int t = threadIdx.x;
  const int lane = t & 63;
  const int w = t >> 6;
  const int wr = w >> 1, wc = w & 1;
  const int m0 = blockIdx.y * 64;
  const int n0 = blockIdx.x * 64;
  const int z = blockIdx.z;

  const u16* Az = Ab + ((size_t)z << 20);
  const u16* Bz = Bb + ((size_t)z << 20);
  const float* bsel = (z == 0) ? b0 : ((z == 1) ? b1 : b2);

  // ---- staging addresses (per-lane global, wave-uniform LDS base) ----
  const int r_abs = w * 16 + (lane >> 2);                 // tile row 0..63
  const int schunk = (lane & 3) ^ ((r_abs >> 1) & 3);     // swizzled source chunk
  const u16* gA = Az + (size_t)(m0 + r_abs) * 1024 + schunk * 8;
  const u16* gB = Bz + (size_t)(n0 + r_abs) * 1024 + schunk * 8;
  u16* ldsA0 = &buf[0][0][(w * 16) * 32];
  u16* ldsA1 = &buf[1][0][(w * 16) * 32];
  u16* ldsB0 = &buf[0][1][(w * 16) * 32];
  u16* ldsB1 = &buf[1][1][(w * 16) * 32];

  // ---- fragment read offsets (swizzled, precomputed) ----
  const int fr = lane & 15;
  const int fq = lane >> 4;
  int offA[2], offB[2];
#pragma unroll
  for (int m = 0; m < 2; m++) {
    const int R = wr * 32 + m * 16 + fr;
    offA[m] = R * 32 + (fq ^ ((R >> 1) & 3)) * 8;
  }
#pragma unroll
  for (int n = 0; n < 2; n++) {
    const int R = wc * 32 + n * 16 + fr;
    offB[n] = R * 32 + (fq ^ ((R >> 1) & 3)) * 8;
  }

  f32x4 acc[2][2];
#pragma unroll
  for (int m = 0; m < 2; m++)
#pragma unroll
    for (int n = 0; n < 2; n++) acc[m][n] = (f32x4){0.f, 0.f, 0.f, 0.f};

  // prologue: stage tile 0
  gload16(gA, ldsA0);
  gload16(gB, ldsB0);
  __syncthreads();

  for (int kt = 0; kt < 32; kt++) {
    const int db = kt & 1;
    if (kt < 31) {   // stage next tile (overlaps with compute below)
      const int k1 = (kt + 1) * 32;
      gload16(gA + k1, db ? ldsA0 : ldsA1);
      gload16(gB + k1, db ? ldsB0 : ldsB1);
    }
    const u16* cA = db ? &buf[1][0][0] : &buf[0][0][0];
    const u16* cB = db ? &buf[1][1][0] : &buf[0][1][0];
    half8v a0 = *(const half8v*)&cA[offA[0]];
    half8v a1 = *(const half8v*)&cA[offA[1]];
    half8v bv0 = *(const half8v*)&cB[offB[0]];
    half8v bv1 = *(const half8v*)&cB[offB[1]];
    acc[0][0] = __builtin_amdgcn_mfma_f32_16x16x32_f16(a0, bv0, acc[0][0], 0, 0, 0);
    acc[0][1] = __builtin_amdgcn_mfma_f32_16x16x32_f16(a0, bv1, acc[0][1], 0, 0, 0);
    acc[1][0] = __builtin_amdgcn_mfma_f32_16x16x32_f16(a1, bv0, acc[1][0], 0, 0, 0);
    acc[1][1] = __builtin_amdgcn_mfma_f32_16x16x32_f16(a1, bv1, acc[1][1], 0, 0, 0);
    __syncthreads();   // drains this step's ds_reads AND the staged loads
  }

  u16*   Cb = (u16*)Cp   + ((size_t)z << 20);
  float* Cf = (float*)Cp + ((size_t)z << 20);

  if (OUT_F16 && z == 2) {
    // transposed store: Vt[col][row]
#pragma unroll
    for (int n = 0; n < 2; n++) {
      const int col = n0 + wc * 32 + n * 16 + fr;
      const float bn = bsel[col];
#pragma unroll
      for (int m = 0; m < 2; m++) {
        const int rbase = m0 + wr * 32 + m * 16 + fq * 4;
        ushort4 pk;
        pk.x = f2h_bits(acc[m][n][0] + bn);
        pk.y = f2h_bits(acc[m][n][1] + bn);
        pk.z = f2h_bits(acc[m][n][2] + bn);
        pk.w = f2h_bits(acc[m][n][3] + bn);
        *(ushort4*)&Cb[(size_t)col * 1024 + rbase] = pk;
      }
    }
    return;
  }

#pragma unroll
  for (int n = 0; n < 2; n++) {
    const int col = n0 + wc * 32 + n * 16 + fr;
    const float bn = bsel[col];
#pragma unroll
    for (int m = 0; m < 2; m++) {
      const int rbase = m0 + wr * 32 + m * 16 + fq * 4;
#pragma unroll
      for (int r = 0; r < 4; r++) {
        const float val = acc[m][n][r] + bn;
        if constexpr (OUT_F16)
          Cb[(size_t)(rbase + r) * 1024 + col] = f2h_bits(val);
        else
          Cf[(size_t)(rbase + r) * 1024 + col] = val;
      }
    }
  }
}

// ---------------------------------------------------------------------------
// Sampled-set bitmask: mask[i] has bit j set iff j ∈ samples[i,:].
// ---------------------------------------------------------------------------
__global__ __launch_bounds__(128) void mask_build(const int* __restrict__ samples,
                                                  uint* __restrict__ maskg) {
  const int i = blockIdx.x;
  const int t = threadIdx.x;
  __shared__ uint m[32];
  if (t < 32) m[t] = 0u;
  __syncthreads();
  const int c = samples[(size_t)i * NS + t];
  atomicOr(&m[c >> 5], 1u << (c & 31));
  __syncthreads();
  if (t < 32) maskg[(size_t)i * 32 + t] = m[t];
}

// ---------------------------------------------------------------------------
// Dense masked attention, f16 MFMA (frozen since R7).
// ---------------------------------------------------------------------------
__global__ __launch_bounds__(128) void attn6(const u16* __restrict__ Qh,
                                             const u16* __restrict__ Kh,
                                             const u16* __restrict__ Vtg,
                                             const uint* __restrict__ maskg,
                                             u16* __restrict__ O) {
  const int h  = blockIdx.x;
  const int qt = blockIdx.y;
  const int t  = threadIdx.x;
  const int wid = t >> 6;
  const int lane = t & 63;
  const int fr = lane & 15, fq = lane >> 4;

  __shared__ u16 Ks[128][72];
  __shared__ u16 Vs[64][136];
  __shared__ u16 Ps[2][16][136];
  __shared__ uint Ms[32][32];

#pragma unroll
  for (int wi = 0; wi < 8; wi++)
    ((uint*)Ms)[wi * 128 + t] = maskg[(size_t)qt * 32 * 32 + wi * 128 + t];

  half8v qa0, qa1;
  {
    const u16* qp = Qh + (size_t)(qt * 32 + wid * 16 + fr) * EMB + h * HD + fq * 8;
    qa0 = *(const half8v*)qp;
    qa1 = *(const half8v*)(qp + 32);
  }

  f32x4 oacc[4];
#pragma unroll
  for (int ds = 0; ds < 4; ds++) oacc[ds] = (f32x4){0.f, 0.f, 0.f, 0.f};
  float lsum[4] = {0.f, 0.f, 0.f, 0.f};

  for (int kt = 0; kt < 8; kt++) {
    __syncthreads();
    {
      const u16* kp = Kh + (size_t)(kt * 128 + (t >> 3)) * EMB + h * HD + (t & 7) * 8;
#pragma unroll
      for (int ii = 0; ii < 8; ii++)
        *(ushort8v*)&Ks[(t >> 3) + ii * 16][(t & 7) * 8] =
            *(const ushort8v*)(kp + (size_t)ii * 16 * EMB);
      const u16* vp = Vtg + (size_t)(h * HD + (t >> 4)) * NTOK + kt * 128 + (t & 15) * 8;
#pragma unroll
      for (int ii = 0; ii < 8; ii++)
        *(ushort8v*)&Vs[(t >> 4) + ii * 8][(t & 15) * 8] =
            *(const ushort8v*)(vp + (size_t)ii * 8 * NTOK);
    }
    __syncthreads();

#pragma unroll
    for (int jb = 0; jb < 8; jb++) {
      f32x4 s = (f32x4){0.f, 0.f, 0.f, 0.f};
      const half8v b0 = *(const half8v*)&Ks[jb * 16 + fr][fq * 8];
      const half8v b1 = *(const half8v*)&Ks[jb * 16 + fr][32 + fq * 8];
      s = __builtin_amdgcn_mfma_f32_16x16x32_f16(qa0, b0, s, 0, 0, 0);
      s = __builtin_amdgcn_mfma_f32_16x16x32_f16(qa1, b1, s, 0, 0, 0);
      const int mword = (kt * 128 + jb * 16) >> 5;
      const int mbit  = (jb & 1) * 16 + fr;
#pragma unroll
      for (int r = 0; r < 4; r++) {
        const uint mw = Ms[wid * 16 + fq * 4 + r][mword];
        const float p = ((mw >> mbit) & 1u) ? __expf(s[r] * 0.03125f) : 0.f;
        lsum[r] += p;
        Ps[wid][fq * 4 + r][jb * 16 + fr] = f2h_bits(p);
      }
    }
    asm volatile("s_waitcnt lgkmcnt(0)" ::: "memory");

#pragma unroll
    for (int jc = 0; jc < 4; jc++) {
      const half8v pa = *(const half8v*)&Ps[wid][fr][jc * 32 + fq * 8];
#pragma unroll
      for (int ds = 0; ds < 4; ds++) {
        const half8v vb = *(const half8v*)&Vs[ds * 16 + fr][jc * 32 + fq * 8];
        oacc[ds] = __builtin_amdgcn_mfma_f32_16x16x32_f16(pa, vb, oacc[ds], 0, 0, 0);
      }
    }
  }

#pragma unroll
  for (int r = 0; r < 4; r++) {
    float v = lsum[r];
#pragma unroll
    for (int off = 1; off < 16; off <<= 1) v += __shfl_xor(v, off, 16);
    lsum[r] = v;
  }

#pragma unroll
  for (int ds = 0; ds < 4; ds++) {
#pragma unroll
    for (int r = 0; r < 4; r++) {
      O[(size_t)(qt * 32 + wid * 16 + fq * 4 + r) * EMB + h * HD + ds * 16 + fr] =
          f2h_bits(oacc[ds][r] / lsum[r]);
    }
  }
}

extern "C" void kernel_launch(void* const* d_in, const int* in_sizes, int n_in,
                              void* d_out, int out_size, void* d_ws, size_t ws_size,
                              hipStream_t stream) {
  const float* query = (const float*)d_in[0];
  const float* key   = (const float*)d_in[1];
  const float* value = (const float*)d_in[2];
  const float* Wq    = (const float*)d_in[3];
  const float* bq    = (const float*)d_in[4];
  const float* Wk    = (const float*)d_in[5];
  const float* bk    = (const float*)d_in[6];
  const float* Wv    = (const float*)d_in[7];
  const float* bv    = (const float*)d_in[8];
  const float* Wo    = (const float*)d_in[9];
  const float* bo    = (const float*)d_in[10];
  const int* samples = (const int*)d_in[11];
  float* out = (float*)d_out;

  // ws (22.1 MB of 256 MiB):
  //   Xh: q/k/v f16 (3 x 1M u16)   at 0
  //   Wh: Wq/Wk/Wv/Wo f16 (4 x 1M) at 3M
  //   Qh,Kh,Vt,O f16 (4 x 1M)      at 7M
  //   mask (32K uint)              at 11M
  u16* base = (u16*)d_ws;
  u16* Xh = base;
  u16* Wh = base + ((size_t)3 << 20);
  u16* Qh = base + ((size_t)7 << 20);
  u16* Kh = base + ((size_t)8 << 20);
  u16* Vt = base + ((size_t)9 << 20);
  u16* O  = base + ((size_t)10 << 20);
  uint* maskg = (uint*)(base + ((size_t)11 << 20));

  mask_build<<<NTOK, NS, 0, stream>>>(samples, maskg);

  cvt7<<<dim3(1024, 7), 256, 0, stream>>>(query, key, value, Wq, Wk, Wv, Wo, Xh);

  // QKV: A = Xh slices, B = Wh slices 0-2, C = Qh/Kh/Vt (z=2 transposed)
  gemm2ph<true><<<dim3(16, 16, 3), 256, 0, stream>>>(Xh, Wh, bq, bk, bv, Qh);

  attn6<<<dim3(NH, 32), 128, 0, stream>>>(Qh, Kh, Vt, maskg, O);

  // out-proj: A = O, B = Wo f16 (slice 3 of Wh), fp32 out
  gemm2ph<false><<<dim3(16, 16, 1), 256, 0, stream>>>(O, Wh + ((size_t)3 << 20), bo, bo, bo, out);
}

// Round 10
// 65.708 us; speedup vs baseline: 1.2185x; 1.0581x over previous
//
#include <hip/hip_runtime.h>
#include <hip/hip_bf16.h>

#define NTOK 1024
#define EMB  1024
#define NH   16
#define HD   64
#define NS   128

typedef unsigned short u16;
typedef unsigned int uint;
typedef __attribute__((ext_vector_type(8))) unsigned short ushort8v;
typedef __attribute__((ext_vector_type(8))) _Float16 half8v;
typedef __attribute__((ext_vector_type(4))) float f32x4;

__device__ __forceinline__ u16 f2h_bits(float f) {
  union { _Float16 h; u16 u; } x; x.h = (_Float16)f; return x.u;
}

__device__ __forceinline__ void gload16(const u16* g, u16* l) {
  __builtin_amdgcn_global_load_lds(
      (const __attribute__((address_space(1))) uint*)g,
      (__attribute__((address_space(3))) uint*)l, 16, 0, 0);
}

// ---------------------------------------------------------------------------
// fp32 -> f16 converter, 7 slices: z 0-2 = query/key/value, 3-6 = Wq/Wk/Wv/Wo.
// ---------------------------------------------------------------------------
__global__ __launch_bounds__(256) void cvt7(const float* __restrict__ S0,
                                            const float* __restrict__ S1,
                                            const float* __restrict__ S2,
                                            const float* __restrict__ S3,
                                            const float* __restrict__ S4,
                                            const float* __restrict__ S5,
                                            const float* __restrict__ S6,
                                            u16* __restrict__ D) {
  const int z = blockIdx.y;
  const float* S;
  switch (z) {
    case 0: S = S0; break;
    case 1: S = S1; break;
    case 2: S = S2; break;
    case 3: S = S3; break;
    case 4: S = S4; break;
    case 5: S = S5; break;
    default: S = S6; break;
  }
  const int idx = blockIdx.x * 256 + threadIdx.x;
  const float4 f = ((const float4*)S)[idx];
  ushort4 p;
  p.x = f2h_bits(f.x); p.y = f2h_bits(f.y);
  p.z = f2h_bits(f.z); p.w = f2h_bits(f.w);
  ((ushort4*)(D + ((size_t)z << 20)))[idx] = p;
}

// ---------------------------------------------------------------------------
// 2-phase double-buffered f16 GEMM (frozen from R9).
// ---------------------------------------------------------------------------
template<bool OUT_F16>
__global__ __launch_bounds__(256) void gemm2ph(const u16* __restrict__ Ab,
                                               const u16* __restrict__ Bb,
                                               const float* __restrict__ b0,
                                               const float* __restrict__ b1,
                                               const float* __restrict__ b2,
                                               void* __restrict__ Cp) {
  __shared__ u16 buf[2][2][64 * 32];

  const int t = threadIdx.x;
  const int lane = t & 63;
  const int w = t >> 6;
  const int wr = w >> 1, wc = w & 1;
  const int m0 = blockIdx.y * 64;
  const int n0 = blockIdx.x * 64;
  const int z = blockIdx.z;

  const u16* Az = Ab + ((size_t)z << 20);
  const u16* Bz = Bb + ((size_t)z << 20);
  const float* bsel = (z == 0) ? b0 : ((z == 1) ? b1 : b2);

  const int r_abs = w * 16 + (lane >> 2);
  const int schunk = (lane & 3) ^ ((r_abs >> 1) & 3);
  const u16* gA = Az + (size_t)(m0 + r_abs) * 1024 + schunk * 8;
  const u16* gB = Bz + (size_t)(n0 + r_abs) * 1024 + schunk * 8;
  u16* ldsA0 = &buf[0][0][(w * 16) * 32];
  u16* ldsA1 = &buf[1][0][(w * 16) * 32];
  u16* ldsB0 = &buf[0][1][(w * 16) * 32];
  u16* ldsB1 = &buf[1][1][(w * 16) * 32];

  const int fr = lane & 15;
  const int fq = lane >> 4;
  int offA[2], offB[2];
#pragma unroll
  for (int m = 0; m < 2; m++) {
    const int R = wr * 32 + m * 16 + fr;
    offA[m] = R * 32 + (fq ^ ((R >> 1) & 3)) * 8;
  }
#pragma unroll
  for (int n = 0; n < 2; n++) {
    const int R = wc * 32 + n * 16 + fr;
    offB[n] = R * 32 + (fq ^ ((R >> 1) & 3)) * 8;
  }

  f32x4 acc[2][2];
#pragma unroll
  for (int m = 0; m < 2; m++)
#pragma unroll
    for (int n = 0; n < 2; n++) acc[m][n] = (f32x4){0.f, 0.f, 0.f, 0.f};

  gload16(gA, ldsA0);
  gload16(gB, ldsB0);
  __syncthreads();

  for (int kt = 0; kt < 32; kt++) {
    const int db = kt & 1;
    if (kt < 31) {
      const int k1 = (kt + 1) * 32;
      gload16(gA + k1, db ? ldsA0 : ldsA1);
      gload16(gB + k1, db ? ldsB0 : ldsB1);
    }
    const u16* cA = db ? &buf[1][0][0] : &buf[0][0][0];
    const u16* cB = db ? &buf[1][1][0] : &buf[0][1][0];
    half8v a0 = *(const half8v*)&cA[offA[0]];
    half8v a1 = *(const half8v*)&cA[offA[1]];
    half8v bv0 = *(const half8v*)&cB[offB[0]];
    half8v bv1 = *(const half8v*)&cB[offB[1]];
    acc[0][0] = __builtin_amdgcn_mfma_f32_16x16x32_f16(a0, bv0, acc[0][0], 0, 0, 0);
    acc[0][1] = __builtin_amdgcn_mfma_f32_16x16x32_f16(a0, bv1, acc[0][1], 0, 0, 0);
    acc[1][0] = __builtin_amdgcn_mfma_f32_16x16x32_f16(a1, bv0, acc[1][0], 0, 0, 0);
    acc[1][1] = __builtin_amdgcn_mfma_f32_16x16x32_f16(a1, bv1, acc[1][1], 0, 0, 0);
    __syncthreads();
  }

  u16*   Cb = (u16*)Cp   + ((size_t)z << 20);
  float* Cf = (float*)Cp + ((size_t)z << 20);

  if (OUT_F16 && z == 2) {
#pragma unroll
    for (int n = 0; n < 2; n++) {
      const int col = n0 + wc * 32 + n * 16 + fr;
      const float bn = bsel[col];
#pragma unroll
      for (int m = 0; m < 2; m++) {
        const int rbase = m0 + wr * 32 + m * 16 + fq * 4;
        ushort4 pk;
        pk.x = f2h_bits(acc[m][n][0] + bn);
        pk.y = f2h_bits(acc[m][n][1] + bn);
        pk.z = f2h_bits(acc[m][n][2] + bn);
        pk.w = f2h_bits(acc[m][n][3] + bn);
        *(ushort4*)&Cb[(size_t)col * 1024 + rbase] = pk;
      }
    }
    return;
  }

#pragma unroll
  for (int n = 0; n < 2; n++) {
    const int col = n0 + wc * 32 + n * 16 + fr;
    const float bn = bsel[col];
#pragma unroll
    for (int m = 0; m < 2; m++) {
      const int rbase = m0 + wr * 32 + m * 16 + fq * 4;
#pragma unroll
      for (int r = 0; r < 4; r++) {
        const float val = acc[m][n][r] + bn;
        if constexpr (OUT_F16)
          Cb[(size_t)(rbase + r) * 1024 + col] = f2h_bits(val);
        else
          Cf[(size_t)(rbase + r) * 1024 + col] = val;
      }
    }
  }
}

// ---------------------------------------------------------------------------
// Sampled-set bitmask.
// ---------------------------------------------------------------------------
__global__ __launch_bounds__(128) void mask_build(const int* __restrict__ samples,
                                                  uint* __restrict__ maskg) {
  const int i = blockIdx.x;
  const int t = threadIdx.x;
  __shared__ uint m[32];
  if (t < 32) m[t] = 0u;
  __syncthreads();
  const int c = samples[(size_t)i * NS + t];
  atomicOr(&m[c >> 5], 1u << (c & 31));
  __syncthreads();
  if (t < 32) maskg[(size_t)i * 32 + t] = m[t];
}

// ---------------------------------------------------------------------------
// attn7: dense masked attention, 64 q-rows/block, 4 waves.
// K/V double-buffered in LDS via global_load_lds with both-sides XOR swizzle
// (K: chunk^=(row&7) on 8x16B rows; V: chunk^=(d&15) on 16x16B rows).
// Counted vmcnt(8) + raw s_barrier per tile (loads stay in flight).
// ---------------------------------------------------------------------------
__global__ __launch_bounds__(256) void attn7(const u16* __restrict__ Qh,
                                             const u16* __restrict__ Kh,
                                             const u16* __restrict__ Vtg,
                                             const uint* __restrict__ maskg,
                                             u16* __restrict__ O) {
  const int h  = blockIdx.x;
  const int qt = blockIdx.y;
  const int t  = threadIdx.x;
  const int wid = t >> 6;
  const int lane = t & 63;
  const int fr = lane & 15, fq = lane >> 4;

  __shared__ u16 Kl[2][128 * 64];    // 32 KB  [key][d] swizzled
  __shared__ u16 Vl[2][64 * 128];    // 32 KB  [d][key] swizzled
  __shared__ u16 Ps[4][16][136];     // 17.4 KB per-wave P
  __shared__ uint Ms[64][32];        // 8 KB mask

  // ---- stage mask (2 x uint4 per thread) ----
  {
    const uint4* src = (const uint4*)(maskg + (size_t)qt * 64 * 32);
    uint4* dst = (uint4*)Ms;
    dst[t * 2]     = src[t * 2];
    dst[t * 2 + 1] = src[t * 2 + 1];
  }

  // ---- Q fragments ----
  half8v qa0, qa1;
  {
    const u16* qp = Qh + (size_t)(qt * 64 + wid * 16 + fr) * EMB + h * HD + fq * 8;
    qa0 = *(const half8v*)qp;
    qa1 = *(const half8v*)(qp + 32);
  }

  // ---- staging lane constants ----
  const int kRow = wid * 32 + (lane >> 3);                 // + ii*8
  const int kChO = ((lane & 7) ^ ((lane >> 3) & 7)) * 8;   // swizzled K chunk
  const u16* kBase = Kh + h * HD + kChO;
  const int vSub = lane >> 4;
  const int vCh  = lane & 15;
  const u16* vBase = Vtg + (size_t)h * HD * NTOK;

  auto STAGE = [&](int kt_, int b_) {
#pragma unroll
    for (int ii = 0; ii < 4; ii++) {
      const int row = kRow + ii * 8;
      gload16(kBase + (size_t)(kt_ * 128 + row) * EMB,
              &Kl[b_][(wid * 32 + ii * 8) * 64]);
    }
#pragma unroll
    for (int ii = 0; ii < 4; ii++) {
      const int d = wid * 16 + ii * 4 + vSub;
      const int ch = (vCh ^ (d & 15)) * 8;
      gload16(vBase + (size_t)d * NTOK + kt_ * 128 + ch,
              &Vl[b_][(wid * 16 + ii * 4) * 128]);
    }
  };

  f32x4 oacc[4];
#pragma unroll
  for (int ds = 0; ds < 4; ds++) oacc[ds] = (f32x4){0.f, 0.f, 0.f, 0.f};
  float lsum[4] = {0.f, 0.f, 0.f, 0.f};

  STAGE(0, 0);

  for (int kt = 0; kt < 8; kt++) {
    if (kt < 7) {
      STAGE(kt + 1, (kt + 1) & 1);
      asm volatile("s_waitcnt vmcnt(8)" ::: "memory");
    } else {
      asm volatile("s_waitcnt vmcnt(0)" ::: "memory");
    }
    asm volatile("s_waitcnt lgkmcnt(0)" ::: "memory");
    __builtin_amdgcn_s_barrier();
    __builtin_amdgcn_sched_barrier(0);

    const u16* Kc = &Kl[kt & 1][0];
    const u16* Vc = &Vl[kt & 1][0];

    // mask words for this ktile (one uint4 per q-row)
    uint4 mq[4];
#pragma unroll
    for (int r = 0; r < 4; r++)
      mq[r] = *(const uint4*)&Ms[wid * 16 + fq * 4 + r][kt * 4];

    // ---- QK^T + mask + exp -> Ps ----
#pragma unroll
    for (int jb = 0; jb < 8; jb++) {
      f32x4 s = (f32x4){0.f, 0.f, 0.f, 0.f};
      const int R = jb * 16 + fr;
      const half8v b0 = *(const half8v*)&Kc[R * 64 + (fq ^ (fr & 7)) * 8];
      const half8v b1 = *(const half8v*)&Kc[R * 64 + ((4 + fq) ^ (fr & 7)) * 8];
      s = __builtin_amdgcn_mfma_f32_16x16x32_f16(qa0, b0, s, 0, 0, 0);
      s = __builtin_amdgcn_mfma_f32_16x16x32_f16(qa1, b1, s, 0, 0, 0);
#pragma unroll
      for (int r = 0; r < 4; r++) {
        const uint mw = (jb >> 1) == 0 ? mq[r].x
                      : (jb >> 1) == 1 ? mq[r].y
                      : (jb >> 1) == 2 ? mq[r].z : mq[r].w;
        const float p = ((mw >> ((jb & 1) * 16 + fr)) & 1u)
                            ? __expf(s[r] * 0.03125f) : 0.f;
        lsum[r] += p;
        Ps[wid][fq * 4 + r][jb * 16 + fr] = f2h_bits(p);
      }
    }
    asm volatile("s_waitcnt lgkmcnt(0)" ::: "memory");
    __builtin_amdgcn_sched_barrier(0);

    // ---- PV ----
#pragma unroll
    for (int jc = 0; jc < 4; jc++) {
      const half8v pa = *(const half8v*)&Ps[wid][fr][jc * 32 + fq * 8];
#pragma unroll
      for (int ds = 0; ds < 4; ds++) {
        const int d = ds * 16 + fr;
        const half8v vb = *(const half8v*)&Vc[d * 128 + ((jc * 4 + fq) ^ fr) * 8];
        oacc[ds] = __builtin_amdgcn_mfma_f32_16x16x32_f16(pa, vb, oacc[ds], 0, 0, 0);
      }
    }
    __builtin_amdgcn_s_barrier();   // all waves done reading buf[kt&1]
  }

  // ---- row-sum reduce (16 lanes sharing a q-row group) ----
#pragma unroll
  for (int r = 0; r < 4; r++) {
    float v = lsum[r];
#pragma unroll
    for (int off = 1; off < 16; off <<= 1) v += __shfl_xor(v, off, 16);
    lsum[r] = v;
  }

#pragma unroll
  for (int ds = 0; ds < 4; ds++) {
#pragma unroll
    for (int r = 0; r < 4; r++) {
      O[(size_t)(qt * 64 + wid * 16 + fq * 4 + r) * EMB + h * HD + ds * 16 + fr] =
          f2h_bits(oacc[ds][r] / lsum[r]);
    }
  }
}

extern "C" void kernel_launch(void* const* d_in, const int* in_sizes, int n_in,
                              void* d_out, int out_size, void* d_ws, size_t ws_size,
                              hipStream_t stream) {
  const float* query = (const float*)d_in[0];
  const float* key   = (const float*)d_in[1];
  const float* value = (const float*)d_in[2];
  const float* Wq    = (const float*)d_in[3];
  const float* bq    = (const float*)d_in[4];
  const float* Wk    = (const float*)d_in[5];
  const float* bk    = (const float*)d_in[6];
  const float* Wv    = (const float*)d_in[7];
  const float* bv    = (const float*)d_in[8];
  const float* Wo    = (const float*)d_in[9];
  const float* bo    = (const float*)d_in[10];
  const int* samples = (const int*)d_in[11];
  float* out = (float*)d_out;

  u16* base = (u16*)d_ws;
  u16* Xh = base;
  u16* Wh = base + ((size_t)3 << 20);
  u16* Qh = base + ((size_t)7 << 20);
  u16* Kh = base + ((size_t)8 << 20);
  u16* Vt = base + ((size_t)9 << 20);
  u16* O  = base + ((size_t)10 << 20);
  uint* maskg = (uint*)(base + ((size_t)11 << 20));

  mask_build<<<NTOK, NS, 0, stream>>>(samples, maskg);

  cvt7<<<dim3(1024, 7), 256, 0, stream>>>(query, key, value, Wq, Wk, Wv, Wo, Xh);

  gemm2ph<true><<<dim3(16, 16, 3), 256, 0, stream>>>(Xh, Wh, bq, bk, bv, Qh);

  attn7<<<dim3(NH, 16), 256, 0, stream>>>(Qh, Kh, Vt, maskg, O);

  gemm2ph<false><<<dim3(16, 16, 1), 256, 0, stream>>>(O, Wh + ((size_t)3 << 20), bo, bo, bo, out);
}

// Round 11
// 59.025 us; speedup vs baseline: 1.3565x; 1.1132x over previous
//
#include <hip/hip_runtime.h>
#include <hip/hip_bf16.h>

#define NTOK 1024
#define EMB  1024
#define NH   16
#define HD   64
#define NS   128

typedef unsigned short u16;
typedef unsigned int uint;
typedef __attribute__((ext_vector_type(8))) unsigned short ushort8v;
typedef __attribute__((ext_vector_type(8))) _Float16 half8v;
typedef __attribute__((ext_vector_type(4))) float f32x4;

__device__ __forceinline__ u16 f2h_bits(float f) {
  union { _Float16 h; u16 u; } x; x.h = (_Float16)f; return x.u;
}

__device__ __forceinline__ void gload16(const u16* g, u16* l) {
  __builtin_amdgcn_global_load_lds(
      (const __attribute__((address_space(1))) uint*)g,
      (__attribute__((address_space(3))) uint*)l, 16, 0, 0);
}

// ---------------------------------------------------------------------------
// cvt_mask: z 0-2 = query/key/value fp32->f16, z 3-6 = Wq/Wk/Wv/Wo fp32->f16,
// z 7 = sampled-set bitmask build (token = blockIdx.x, threads 0-127).
// ---------------------------------------------------------------------------
__global__ __launch_bounds__(256) void cvt_mask(const float* __restrict__ S0,
                                                const float* __restrict__ S1,
                                                const float* __restrict__ S2,
                                                const float* __restrict__ S3,
                                                const float* __restrict__ S4,
                                                const float* __restrict__ S5,
                                                const float* __restrict__ S6,
                                                const int* __restrict__ samples,
                                                u16* __restrict__ D,
                                                uint* __restrict__ maskg) {
  const int z = blockIdx.y;
  const int t = threadIdx.x;
  if (z == 7) {
    __shared__ uint m[32];
    const int i = blockIdx.x;
    if (t < 32) m[t] = 0u;
    __syncthreads();
    if (t < NS) {
      const int c = samples[(size_t)i * NS + t];
      atomicOr(&m[c >> 5], 1u << (c & 31));
    }
    __syncthreads();
    if (t < 32) maskg[(size_t)i * 32 + t] = m[t];
    return;
  }
  const float* S;
  switch (z) {
    case 0: S = S0; break;
    case 1: S = S1; break;
    case 2: S = S2; break;
    case 3: S = S3; break;
    case 4: S = S4; break;
    case 5: S = S5; break;
    default: S = S6; break;
  }
  const int idx = blockIdx.x * 256 + t;
  const float4 f = ((const float4*)S)[idx];
  ushort4 p;
  p.x = f2h_bits(f.x); p.y = f2h_bits(f.y);
  p.z = f2h_bits(f.z); p.w = f2h_bits(f.w);
  ((ushort4*)(D + ((size_t)z << 20)))[idx] = p;
}

// ---------------------------------------------------------------------------
// Counted-vmcnt double-buffered f16 GEMM: C = A*B^T + bias, 1024^3.
// 64x64 tile, BK=32, 4 waves. Per K-step: issue next tile's global_load_lds,
// s_waitcnt vmcnt(2) (current tile landed, next stays IN FLIGHT across the
// raw s_barrier -- no drain), compute, lgkmcnt(0)+s_barrier (reuse guard).
// Both-sides XOR swizzle as R9. OUT_F16 && z==2 stores C transposed.
// ---------------------------------------------------------------------------
template<bool OUT_F16>
__global__ __launch_bounds__(256) void gemm3(const u16* __restrict__ Ab,
                                             const u16* __restrict__ Bb,
                                             const float* __restrict__ b0,
                                             const float* __restrict__ b1,
                                             const float* __restrict__ b2,
                                             void* __restrict__ Cp) {
  __shared__ u16 buf[2][2][64 * 32];

  const int t = threadIdx.x;
  const int lane = t & 63;
  const int w = t >> 6;
  const int wr = w >> 1, wc = w & 1;
  const int m0 = blockIdx.y * 64;
  const int n0 = blockIdx.x * 64;
  const int z = blockIdx.z;

  const u16* Az = Ab + ((size_t)z << 20);
  const u16* Bz = Bb + ((size_t)z << 20);
  const float* bsel = (z == 0) ? b0 : ((z == 1) ? b1 : b2);

  const int r_abs = w * 16 + (lane >> 2);
  const int schunk = (lane & 3) ^ ((r_abs >> 1) & 3);
  const u16* gA = Az + (size_t)(m0 + r_abs) * 1024 + schunk * 8;
  const u16* gB = Bz + (size_t)(n0 + r_abs) * 1024 + schunk * 8;
  u16* ldsA[2] = { &buf[0][0][(w * 16) * 32], &buf[1][0][(w * 16) * 32] };
  u16* ldsB[2] = { &buf[0][1][(w * 16) * 32], &buf[1][1][(w * 16) * 32] };

  const int fr = lane & 15;
  const int fq = lane >> 4;
  int offA[2], offB[2];
#pragma unroll
  for (int m = 0; m < 2; m++) {
    const int R = wr * 32 + m * 16 + fr;
    offA[m] = R * 32 + (fq ^ ((R >> 1) & 3)) * 8;
  }
#pragma unroll
  for (int n = 0; n < 2; n++) {
    const int R = wc * 32 + n * 16 + fr;
    offB[n] = R * 32 + (fq ^ ((R >> 1) & 3)) * 8;
  }

  f32x4 acc[2][2];
#pragma unroll
  for (int m = 0; m < 2; m++)
#pragma unroll
    for (int n = 0; n < 2; n++) acc[m][n] = (f32x4){0.f, 0.f, 0.f, 0.f};

  // prologue: stage tile 0
  gload16(gA, ldsA[0]);
  gload16(gB, ldsB[0]);

  for (int kt = 0; kt < 32; kt++) {
    const int db = kt & 1;
    if (kt < 31) {
      const int k1 = (kt + 1) * 32;
      gload16(gA + k1, ldsA[db ^ 1]);
      gload16(gB + k1, ldsB[db ^ 1]);
      asm volatile("s_waitcnt vmcnt(2)" ::: "memory");  // kt landed; kt+1 in flight
    } else {
      asm volatile("s_waitcnt vmcnt(0)" ::: "memory");
    }
    __builtin_amdgcn_s_barrier();        // all waves: buf[db] ready
    __builtin_amdgcn_sched_barrier(0);

    const u16* cA = &buf[db][0][0];
    const u16* cB = &buf[db][1][0];
    half8v a0 = *(const half8v*)&cA[offA[0]];
    half8v a1 = *(const half8v*)&cA[offA[1]];
    half8v bv0 = *(const half8v*)&cB[offB[0]];
    half8v bv1 = *(const half8v*)&cB[offB[1]];
    acc[0][0] = __builtin_amdgcn_mfma_f32_16x16x32_f16(a0, bv0, acc[0][0], 0, 0, 0);
    acc[0][1] = __builtin_amdgcn_mfma_f32_16x16x32_f16(a0, bv1, acc[0][1], 0, 0, 0);
    acc[1][0] = __builtin_amdgcn_mfma_f32_16x16x32_f16(a1, bv0, acc[1][0], 0, 0, 0);
    acc[1][1] = __builtin_amdgcn_mfma_f32_16x16x32_f16(a1, bv1, acc[1][1], 0, 0, 0);

    asm volatile("s_waitcnt lgkmcnt(0)" ::: "memory");  // this tile's ds_reads done
    __builtin_amdgcn_s_barrier();        // safe for kt+2 to overwrite buf[db]
    __builtin_amdgcn_sched_barrier(0);
  }

  u16*   Cb = (u16*)Cp   + ((size_t)z << 20);
  float* Cf = (float*)Cp + ((size_t)z << 20);

  if (OUT_F16 && z == 2) {
#pragma unroll
    for (int n = 0; n < 2; n++) {
      const int col = n0 + wc * 32 + n * 16 + fr;
      const float bn = bsel[col];
#pragma unroll
      for (int m = 0; m < 2; m++) {
        const int rbase = m0 + wr * 32 + m * 16 + fq * 4;
        ushort4 pk;
        pk.x = f2h_bits(acc[m][n][0] + bn);
        pk.y = f2h_bits(acc[m][n][1] + bn);
        pk.z = f2h_bits(acc[m][n][2] + bn);
        pk.w = f2h_bits(acc[m][n][3] + bn);
        *(ushort4*)&Cb[(size_t)col * 1024 + rbase] = pk;
      }
    }
    return;
  }

#pragma unroll
  for (int n = 0; n < 2; n++) {
    const int col = n0 + wc * 32 + n * 16 + fr;
    const float bn = bsel[col];
#pragma unroll
    for (int m = 0; m < 2; m++) {
      const int rbase = m0 + wr * 32 + m * 16 + fq * 4;
#pragma unroll
      for (int r = 0; r < 4; r++) {
        const float val = acc[m][n][r] + bn;
        if constexpr (OUT_F16)
          Cb[(size_t)(rbase + r) * 1024 + col] = f2h_bits(val);
        else
          Cf[(size_t)(rbase + r) * 1024 + col] = val;
      }
    }
  }
}

// ---------------------------------------------------------------------------
// attn7: dense masked attention (frozen from R10).
// ---------------------------------------------------------------------------
__global__ __launch_bounds__(256) void attn7(const u16* __restrict__ Qh,
                                             const u16* __restrict__ Kh,
                                             const u16* __restrict__ Vtg,
                                             const uint* __restrict__ maskg,
                                             u16* __restrict__ O) {
  const int h  = blockIdx.x;
  const int qt = blockIdx.y;
  const int t  = threadIdx.x;
  const int wid = t >> 6;
  const int lane = t & 63;
  const int fr = lane & 15, fq = lane >> 4;

  __shared__ u16 Kl[2][128 * 64];
  __shared__ u16 Vl[2][64 * 128];
  __shared__ u16 Ps[4][16][136];
  __shared__ uint Ms[64][32];

  {
    const uint4* src = (const uint4*)(maskg + (size_t)qt * 64 * 32);
    uint4* dst = (uint4*)Ms;
    dst[t * 2]     = src[t * 2];
    dst[t * 2 + 1] = src[t * 2 + 1];
  }

  half8v qa0, qa1;
  {
    const u16* qp = Qh + (size_t)(qt * 64 + wid * 16 + fr) * EMB + h * HD + fq * 8;
    qa0 = *(const half8v*)qp;
    qa1 = *(const half8v*)(qp + 32);
  }

  const int kRow = wid * 32 + (lane >> 3);
  const int kChO = ((lane & 7) ^ ((lane >> 3) & 7)) * 8;
  const u16* kBase = Kh + h * HD + kChO;
  const int vSub = lane >> 4;
  const int vCh  = lane & 15;
  const u16* vBase = Vtg + (size_t)h * HD * NTOK;

  auto STAGE = [&](int kt_, int b_) {
#pragma unroll
    for (int ii = 0; ii < 4; ii++) {
      const int row = kRow + ii * 8;
      gload16(kBase + (size_t)(kt_ * 128 + row) * EMB,
              &Kl[b_][(wid * 32 + ii * 8) * 64]);
    }
#pragma unroll
    for (int ii = 0; ii < 4; ii++) {
      const int d = wid * 16 + ii * 4 + vSub;
      const int ch = (vCh ^ (d & 15)) * 8;
      gload16(vBase + (size_t)d * NTOK + kt_ * 128 + ch,
              &Vl[b_][(wid * 16 + ii * 4) * 128]);
    }
  };

  f32x4 oacc[4];
#pragma unroll
  for (int ds = 0; ds < 4; ds++) oacc[ds] = (f32x4){0.f, 0.f, 0.f, 0.f};
  float lsum[4] = {0.f, 0.f, 0.f, 0.f};

  STAGE(0, 0);

  for (int kt = 0; kt < 8; kt++) {
    if (kt < 7) {
      STAGE(kt + 1, (kt + 1) & 1);
      asm volatile("s_waitcnt vmcnt(8)" ::: "memory");
    } else {
      asm volatile("s_waitcnt vmcnt(0)" ::: "memory");
    }
    asm volatile("s_waitcnt lgkmcnt(0)" ::: "memory");
    __builtin_amdgcn_s_barrier();
    __builtin_amdgcn_sched_barrier(0);

    const u16* Kc = &Kl[kt & 1][0];
    const u16* Vc = &Vl[kt & 1][0];

    uint4 mq[4];
#pragma unroll
    for (int r = 0; r < 4; r++)
      mq[r] = *(const uint4*)&Ms[wid * 16 + fq * 4 + r][kt * 4];

#pragma unroll
    for (int jb = 0; jb < 8; jb++) {
      f32x4 s = (f32x4){0.f, 0.f, 0.f, 0.f};
      const int R = jb * 16 + fr;
      const half8v b0 = *(const half8v*)&Kc[R * 64 + (fq ^ (fr & 7)) * 8];
      const half8v b1 = *(const half8v*)&Kc[R * 64 + ((4 + fq) ^ (fr & 7)) * 8];
      s = __builtin_amdgcn_mfma_f32_16x16x32_f16(qa0, b0, s, 0, 0, 0);
      s = __builtin_amdgcn_mfma_f32_16x16x32_f16(qa1, b1, s, 0, 0, 0);
#pragma unroll
      for (int r = 0; r < 4; r++) {
        const uint mw = (jb >> 1) == 0 ? mq[r].x
                      : (jb >> 1) == 1 ? mq[r].y
                      : (jb >> 1) == 2 ? mq[r].z : mq[r].w;
        const float p = ((mw >> ((jb & 1) * 16 + fr)) & 1u)
                            ? __expf(s[r] * 0.03125f) : 0.f;
        lsum[r] += p;
        Ps[wid][fq * 4 + r][jb * 16 + fr] = f2h_bits(p);
      }
    }
    asm volatile("s_waitcnt lgkmcnt(0)" ::: "memory");
    __builtin_amdgcn_sched_barrier(0);

#pragma unroll
    for (int jc = 0; jc < 4; jc++) {
      const half8v pa = *(const half8v*)&Ps[wid][fr][jc * 32 + fq * 8];
#pragma unroll
      for (int ds = 0; ds < 4; ds++) {
        const int d = ds * 16 + fr;
        const half8v vb = *(const half8v*)&Vc[d * 128 + ((jc * 4 + fq) ^ fr) * 8];
        oacc[ds] = __builtin_amdgcn_mfma_f32_16x16x32_f16(pa, vb, oacc[ds], 0, 0, 0);
      }
    }
    __builtin_amdgcn_s_barrier();
  }

#pragma unroll
  for (int r = 0; r < 4; r++) {
    float v = lsum[r];
#pragma unroll
    for (int off = 1; off < 16; off <<= 1) v += __shfl_xor(v, off, 16);
    lsum[r] = v;
  }

#pragma unroll
  for (int ds = 0; ds < 4; ds++) {
#pragma unroll
    for (int r = 0; r < 4; r++) {
      O[(size_t)(qt * 64 + wid * 16 + fq * 4 + r) * EMB + h * HD + ds * 16 + fr] =
          f2h_bits(oacc[ds][r] / lsum[r]);
    }
  }
}

extern "C" void kernel_launch(void* const* d_in, const int* in_sizes, int n_in,
                              void* d_out, int out_size, void* d_ws, size_t ws_size,
                              hipStream_t stream) {
  const float* query = (const float*)d_in[0];
  const float* key   = (const float*)d_in[1];
  const float* value = (const float*)d_in[2];
  const float* Wq    = (const float*)d_in[3];
  const float* bq    = (const float*)d_in[4];
  const float* Wk    = (const float*)d_in[5];
  const float* bk    = (const float*)d_in[6];
  const float* Wv    = (const float*)d_in[7];
  const float* bv    = (const float*)d_in[8];
  const float* Wo    = (const float*)d_in[9];
  const float* bo    = (const float*)d_in[10];
  const int* samples = (const int*)d_in[11];
  float* out = (float*)d_out;

  u16* base = (u16*)d_ws;
  u16* Xh = base;                              // q/k/v f16 (3 slices)
  u16* Wh = base + ((size_t)3 << 20);          // Wq/Wk/Wv/Wo f16 (4 slices)
  u16* Qh = base + ((size_t)7 << 20);
  u16* Kh = base + ((size_t)8 << 20);
  u16* Vt = base + ((size_t)9 << 20);
  u16* O  = base + ((size_t)10 << 20);
  uint* maskg = (uint*)(base + ((size_t)11 << 20));

  cvt_mask<<<dim3(1024, 8), 256, 0, stream>>>(
      query, key, value, Wq, Wk, Wv, Wo, samples, Xh, maskg);

  gemm3<true><<<dim3(16, 16, 3), 256, 0, stream>>>(Xh, Wh, bq, bk, bv, Qh);

  attn7<<<dim3(NH, 16), 256, 0, stream>>>(Qh, Kh, Vt, maskg, O);

  gemm3<false><<<dim3(16, 16, 1), 256, 0, stream>>>(O, Wh + ((size_t)3 << 20), bo, bo, bo, out);
}